// Round 1
// baseline (362.176 us; speedup 1.0000x reference)
//
#include <hip/hip_runtime.h>
#include <hip/hip_bf16.h>

#define L_ 64
#define B_ 32
#define S_ 64
#define D_ 512
#define V_ 32000
#define NL_ 2

typedef __attribute__((ext_vector_type(8))) short bf16x8;
typedef __attribute__((ext_vector_type(4))) float f32x4;

static __device__ __forceinline__ short f2bf(float f) {
  union { float f; unsigned u; } x; x.f = f;
  unsigned r = (x.u + 0x7FFFu + ((x.u >> 16) & 1u)) >> 16;
  return (short)r;
}

#define GLOAD_LDS16(g, l)                                                     \
  __builtin_amdgcn_global_load_lds(                                           \
      (const __attribute__((address_space(1))) void*)(g),                     \
      (__attribute__((address_space(3))) void*)(l), 16, 0, 0)

// ---------------- embedding gather: x[l,b,d] = tab[tok[l,b], d] -------------
__global__ void embed_kernel(const int* __restrict__ tok, const float* __restrict__ tab,
                             float* __restrict__ xf, short* __restrict__ xb) {
  int i = blockIdx.x * 256 + threadIdx.x;  // < L*B*D = 1048576
  int d = i & (D_ - 1);
  int lb = i >> 9;
  float v = tab[(size_t)tok[lb] * D_ + d];
  xf[i] = v;
  xb[i] = f2bf(v);
}

// ------------- f32 [K,N] -> bf16 [N,K] transpose (LDS-tiled) ----------------
__global__ void transpose_f32_bf16(const float* __restrict__ in, short* __restrict__ out,
                                   int K, int N) {
  __shared__ float tile[32][33];
  int x = blockIdx.x * 32 + threadIdx.x;  // N index
  int y0 = blockIdx.y * 32;               // K base
  for (int j = threadIdx.y; j < 32; j += 8) {
    int y = y0 + j;
    tile[j][threadIdx.x] = (x < N && y < K) ? in[(size_t)y * N + x] : 0.f;
  }
  __syncthreads();
  int xo = y0 + threadIdx.x;              // K index
  int yo0 = blockIdx.x * 32;              // N base
  for (int j = threadIdx.y; j < 32; j += 8) {
    int yo = yo0 + j;
    if (yo < N && xo < K) out[(size_t)yo * K + xo] = f2bf(tile[threadIdx.x][j]);
  }
}

// ---------------- generic bf16 MFMA GEMM: C = A[M,K] * BT[N,K]^T ------------
// MODE 0: write f32 C[M,N]
// MODE 1: write bf16 tanh(C)[M,N]
// MODE 2: write f32 C[row-remap (l*B+b)->(b*L+l)][N] + bias[n]
#define BM 128
#define BN 128
#define BK 64

template <int MODE>
__global__ __launch_bounds__(256) void gemm_kernel(
    const short* __restrict__ A, const short* __restrict__ BT,
    void* __restrict__ Cptr, const float* __restrict__ bias,
    int M, int N, int K) {
  __shared__ __align__(16) short la[BM * BK];
  __shared__ __align__(16) short lb[BN * BK];
  const int tid = threadIdx.x;
  const int wave = tid >> 6, lane = tid & 63;
  const int bm = blockIdx.y, bn = blockIdx.x;
  const int wm = (wave >> 1) * 64, wn = (wave & 1) * 64;

  f32x4 acc[4][4] = {};

  const int lrow = lane >> 3;   // row within 8-row chunk
  const int lslot = lane & 7;   // 16B slot within 128B row

  for (int k0 = 0; k0 < K; k0 += BK) {
    // stage A and B tiles: 16 chunks of 1KB each (8 rows x 64 bf16),
    // linear LDS dest, XOR-swizzled global source (slot ^= row&7).
#pragma unroll
    for (int c = 0; c < 4; ++c) {
      int chunk = wave * 4 + c;
      int row = chunk * 8 + lrow;
      int slot = lslot ^ (row & 7);
      const short* srcA = A + (size_t)(bm * BM + row) * K + k0 + slot * 8;
      GLOAD_LDS16(srcA, &la[chunk * 512]);
      const short* srcB = BT + (size_t)(bn * BN + row) * K + k0 + slot * 8;
      GLOAD_LDS16(srcB, &lb[chunk * 512]);
    }
    __syncthreads();
#pragma unroll
    for (int kk = 0; kk < 2; ++kk) {
      bf16x8 af[4], bfr[4];
#pragma unroll
      for (int mi = 0; mi < 4; ++mi) {
        int row = wm + mi * 16 + (lane & 15);
        int slot = (kk * 4 + (lane >> 4)) ^ (row & 7);
        af[mi] = *(const bf16x8*)&la[row * 64 + slot * 8];
      }
#pragma unroll
      for (int ni = 0; ni < 4; ++ni) {
        int row = wn + ni * 16 + (lane & 15);
        int slot = (kk * 4 + (lane >> 4)) ^ (row & 7);
        bfr[ni] = *(const bf16x8*)&lb[row * 64 + slot * 8];
      }
#pragma unroll
      for (int mi = 0; mi < 4; ++mi)
#pragma unroll
        for (int ni = 0; ni < 4; ++ni)
          acc[mi][ni] = __builtin_amdgcn_mfma_f32_16x16x32_bf16(
              af[mi], bfr[ni], acc[mi][ni], 0, 0, 0);
    }
    __syncthreads();
  }

  const int cl = lane & 15;
  const int rl = (lane >> 4) * 4;
#pragma unroll
  for (int mi = 0; mi < 4; ++mi) {
#pragma unroll
    for (int ni = 0; ni < 4; ++ni) {
      int c = bn * BN + wn + ni * 16 + cl;
      int r0 = bm * BM + wm + mi * 16 + rl;
#pragma unroll
      for (int j = 0; j < 4; ++j) {
        int r = r0 + j;
        float v = acc[mi][ni][j];
        if (MODE == 0) {
          ((float*)Cptr)[(size_t)r * N + c] = v;
        } else if (MODE == 1) {
          ((short*)Cptr)[(size_t)r * N + c] = f2bf(tanhf(v));
        } else {
          int b = r & 31, l = r >> 5;
          ((float*)Cptr)[(size_t)(b * L_ + l) * N + c] = v + bias[c];
        }
      }
    }
  }
}

// ---------------- SRU scan: per (b,d) lane, sequential over L ---------------
__global__ void sru_scan_kernel(const float* __restrict__ U, const float* __restrict__ bvec,
                                const float* __restrict__ xin, const float* __restrict__ c0,
                                float* __restrict__ hf, short* __restrict__ hb,
                                float* __restrict__ clast) {
  int idx = blockIdx.x * 256 + threadIdx.x;  // < B*D = 16384
  int b = idx >> 9, d = idx & 511;
  float c = c0[idx];
  float bfb = bvec[d], brb = bvec[512 + d];
#pragma unroll 4
  for (int l = 0; l < L_; ++l) {
    size_t u = ((size_t)l * B_ + b) * 1536;
    float z = U[u + d];
    float fp = U[u + 512 + d];
    float rp = U[u + 1024 + d];
    float f = 1.f / (1.f + expf(-(fp + bfb)));
    float r = 1.f / (1.f + expf(-(rp + brb)));
    c = f * c + (1.f - f) * z;
    float x = xin[((size_t)l * B_ + b) * 512 + d];
    float h = r * tanhf(c) + (1.f - r) * x;
    size_t o = ((size_t)l * B_ + b) * 512 + d;
    hf[o] = h;
    hb[o] = f2bf(h);
  }
  clast[idx] = c;
}

// -------- fused scores + softmax: one wave per (l,b) row --------------------
__global__ void scores_softmax_kernel(const float* __restrict__ x, const float* __restrict__ enc,
                                      float* __restrict__ align_out) {
  __shared__ float q[512];
  int r = blockIdx.x;       // l*B + b
  int b = r & (B_ - 1);
  int tid = threadIdx.x;    // 64 = one wave
  for (int d = tid; d < 512; d += 64) q[d] = x[(size_t)r * 512 + d];
  __syncthreads();
  const float* m = enc + ((size_t)tid * B_ + b) * 512;
  float acc = 0.f;
  for (int d = 0; d < 512; ++d) acc += q[d] * m[d];
  float mx = acc;
  for (int o = 32; o > 0; o >>= 1) mx = fmaxf(mx, __shfl_xor(mx, o));
  float e = expf(acc - mx);
  float sm = e;
  for (int o = 32; o > 0; o >>= 1) sm += __shfl_xor(sm, o);
  align_out[(size_t)r * S_ + tid] = e / sm;
}

// -------- ctx = align @ mem, then concat [ctx, q] as bf16 -------------------
__global__ void ctx_concat_kernel(const float* __restrict__ align_in, const float* __restrict__ enc,
                                  const short* __restrict__ xb, short* __restrict__ cat) {
  __shared__ float al[64];
  int r = blockIdx.x;       // l*B + b
  int b = r & (B_ - 1);
  int tid = threadIdx.x;    // 256
  if (tid < 64) al[tid] = align_in[(size_t)r * S_ + tid];
  __syncthreads();
  for (int d = tid; d < 512; d += 256) {
    float acc = 0.f;
#pragma unroll 8
    for (int s = 0; s < S_; ++s) acc += al[s] * enc[((size_t)s * B_ + b) * 512 + d];
    cat[(size_t)r * 1024 + d] = f2bf(acc);
    cat[(size_t)r * 1024 + 512 + d] = xb[(size_t)r * 512 + d];
  }
}

extern "C" void kernel_launch(void* const* d_in, const int* in_sizes, int n_in,
                              void* d_out, int out_size, void* d_ws, size_t ws_size,
                              hipStream_t stream) {
  const int* rnn = (const int*)d_in[0];
  const float* h0 = (const float*)d_in[1];
  const float* enc = (const float*)d_in[2];
  const float* tab = (const float*)d_in[3];
  const float* sruW = (const float*)d_in[4];
  const float* srub = (const float*)d_in[5];
  const float* attnW = (const float*)d_in[6];
  const float* outW = (const float*)d_in[7];
  const float* outb = (const float*)d_in[8];
  float* out = (float*)d_out;

  char* ws = (char*)d_ws;
  size_t off = 0;
  auto alloc = [&](size_t bytes) {
    char* p = ws + off;
    off += (bytes + 255) & ~(size_t)255;
    return p;
  };
  float* xf = (float*)alloc(4ull * 2048 * 512);
  float* xf2 = (float*)alloc(4ull * 2048 * 512);
  short* xb = (short*)alloc(2ull * 2048 * 512);
  float* U = (float*)alloc(4ull * 2048 * 1536);
  short* WTs = (short*)alloc(2ull * 2 * 1536 * 512);
  short* WTa = (short*)alloc(2ull * 512 * 1024);
  short* WTo = (short*)alloc(2ull * 32000 * 512);
  float* algn = (float*)alloc(4ull * 2048 * 64);
  short* cat = (short*)alloc(2ull * 2048 * 1024);
  short* ah = (short*)alloc(2ull * 2048 * 512);

  dim3 tb(32, 8);
  for (int l = 0; l < NL_; ++l)
    transpose_f32_bf16<<<dim3(48, 16), tb, 0, stream>>>(
        sruW + (size_t)l * 512 * 1536, WTs + (size_t)l * 1536 * 512, 512, 1536);
  transpose_f32_bf16<<<dim3(16, 32), tb, 0, stream>>>(attnW, WTa, 1024, 512);
  transpose_f32_bf16<<<dim3(1000, 16), tb, 0, stream>>>(outW, WTo, 512, 32000);

  embed_kernel<<<4096, 256, 0, stream>>>(rnn, tab, xf, xb);

  float* hidden_out = out + (size_t)B_ * L_ * V_;

  // layer 0: x(=embed) -> h in xf2/xb
  gemm_kernel<0><<<dim3(12, 16), 256, 0, stream>>>(xb, WTs, U, nullptr, 2048, 1536, 512);
  sru_scan_kernel<<<64, 256, 0, stream>>>(U, srub, xf, h0, xf2, xb, hidden_out);
  // layer 1: h1 -> final h in xf/xb
  gemm_kernel<0><<<dim3(12, 16), 256, 0, stream>>>(xb, WTs + 1536 * 512, U, nullptr, 2048, 1536, 512);
  sru_scan_kernel<<<64, 256, 0, stream>>>(U, srub + 1024, xf2, h0 + B_ * D_, xf, xb,
                                          hidden_out + B_ * D_);

  scores_softmax_kernel<<<2048, 64, 0, stream>>>(xf, enc, algn);
  ctx_concat_kernel<<<2048, 256, 0, stream>>>(algn, enc, xb, cat);

  // attn_h = tanh(concat @ attn_W) as bf16
  gemm_kernel<1><<<dim3(4, 16), 256, 0, stream>>>(cat, WTa, ah, nullptr, 2048, 512, 1024);
  // output = attn_h @ out_W + out_b, remapped to [B,L,V]
  gemm_kernel<2><<<dim3(250, 16), 256, 0, stream>>>(ah, WTo, out, outb, 2048, 32000, 512);
}

// Round 2
// 330.535 us; speedup vs baseline: 1.0957x; 1.0957x over previous
//
#include <hip/hip_runtime.h>
#include <hip/hip_bf16.h>

#define L_ 64
#define B_ 32
#define S_ 64
#define D_ 512
#define V_ 32000
#define NL_ 2

typedef __attribute__((ext_vector_type(8))) short bf16x8;
typedef __attribute__((ext_vector_type(4))) float f32x4;

static __device__ __forceinline__ short f2bf(float f) {
  union { float f; unsigned u; } x; x.f = f;
  unsigned r = (x.u + 0x7FFFu + ((x.u >> 16) & 1u)) >> 16;
  return (short)r;
}

#define GLOAD_LDS16(g, l)                                                     \
  __builtin_amdgcn_global_load_lds(                                           \
      (const __attribute__((address_space(1))) void*)(g),                     \
      (__attribute__((address_space(3))) void*)(l), 16, 0, 0)

// ---------------- embedding gather: x[l,b,d] = tab[tok[l,b], d] -------------
__global__ void embed_kernel(const int* __restrict__ tok, const float* __restrict__ tab,
                             float* __restrict__ xf, short* __restrict__ xb) {
  int i = blockIdx.x * 256 + threadIdx.x;  // < L*B*D = 1048576
  int d = i & (D_ - 1);
  int lb = i >> 9;
  float v = tab[(size_t)tok[lb] * D_ + d];
  xf[i] = v;
  xb[i] = f2bf(v);
}

// ------------- f32 [K,N] -> bf16 [N,K] transpose (LDS-tiled) ----------------
__global__ void transpose_f32_bf16(const float* __restrict__ in, short* __restrict__ out,
                                   int K, int N) {
  __shared__ float tile[32][33];
  int x = blockIdx.x * 32 + threadIdx.x;  // N index
  int y0 = blockIdx.y * 32;               // K base
  for (int j = threadIdx.y; j < 32; j += 8) {
    int y = y0 + j;
    tile[j][threadIdx.x] = (x < N && y < K) ? in[(size_t)y * N + x] : 0.f;
  }
  __syncthreads();
  int xo = y0 + threadIdx.x;              // K index
  int yo0 = blockIdx.x * 32;              // N base
  for (int j = threadIdx.y; j < 32; j += 8) {
    int yo = yo0 + j;
    if (yo < N && xo < K) out[(size_t)yo * K + xo] = f2bf(tile[threadIdx.x][j]);
  }
}

// ---------------- generic bf16 MFMA GEMM: C = A[M,K] * BT[N,K]^T ------------
// Flat grid, XCD-chunked bijective swizzle, bm-fastest within a chunk so
// consecutive blocks share a B-tile (L2 reuse) and each XCD's L2 holds a
// contiguous slice of B.
// MODE 0: write f32 C[M,N]
// MODE 1: write bf16 tanh(C)[M,N]
// MODE 2: write f32 C[row-remap (l*B+b)->(b*L+l)][N] + bias[n]
#define BM 128
#define BN 128
#define BK 64

template <int MODE>
__global__ __launch_bounds__(256) void gemm_kernel(
    const short* __restrict__ A, const short* __restrict__ BT,
    void* __restrict__ Cptr, const float* __restrict__ bias,
    int M, int N, int K, int nbm) {
  // ---- XCD-chunked swizzle (requires gridDim.x % 8 == 0) ----
  const int nwg = gridDim.x;
  const int qc = nwg >> 3;
  const int bid = blockIdx.x;
  const int wg = (bid & 7) * qc + (bid >> 3);
  const int bm = wg % nbm;
  const int bn = wg / nbm;

  __shared__ __align__(16) short la[BM * BK];
  __shared__ __align__(16) short lb[BN * BK];
  const int tid = threadIdx.x;
  const int wave = tid >> 6, lane = tid & 63;
  const int wm = (wave >> 1) * 64, wn = (wave & 1) * 64;

  f32x4 acc[4][4] = {};

  const int lrow = lane >> 3;   // row within 8-row chunk
  const int lslot = lane & 7;   // 16B slot within 128B row

  for (int k0 = 0; k0 < K; k0 += BK) {
    // stage A and B tiles: 16 chunks of 1KB each (8 rows x 64 bf16),
    // linear LDS dest, XOR-swizzled global source (slot ^= row&7).
#pragma unroll
    for (int c = 0; c < 4; ++c) {
      int chunk = wave * 4 + c;
      int row = chunk * 8 + lrow;
      int slot = lslot ^ (row & 7);
      const short* srcA = A + (size_t)(bm * BM + row) * K + k0 + slot * 8;
      GLOAD_LDS16(srcA, &la[chunk * 512]);
      const short* srcB = BT + (size_t)(bn * BN + row) * K + k0 + slot * 8;
      GLOAD_LDS16(srcB, &lb[chunk * 512]);
    }
    __syncthreads();
#pragma unroll
    for (int kk = 0; kk < 2; ++kk) {
      bf16x8 af[4], bfr[4];
#pragma unroll
      for (int mi = 0; mi < 4; ++mi) {
        int row = wm + mi * 16 + (lane & 15);
        int slot = (kk * 4 + (lane >> 4)) ^ (row & 7);
        af[mi] = *(const bf16x8*)&la[row * 64 + slot * 8];
      }
#pragma unroll
      for (int ni = 0; ni < 4; ++ni) {
        int row = wn + ni * 16 + (lane & 15);
        int slot = (kk * 4 + (lane >> 4)) ^ (row & 7);
        bfr[ni] = *(const bf16x8*)&lb[row * 64 + slot * 8];
      }
#pragma unroll
      for (int mi = 0; mi < 4; ++mi)
#pragma unroll
        for (int ni = 0; ni < 4; ++ni)
          acc[mi][ni] = __builtin_amdgcn_mfma_f32_16x16x32_bf16(
              af[mi], bfr[ni], acc[mi][ni], 0, 0, 0);
    }
    __syncthreads();
  }

  const int cl = lane & 15;
  const int rl = (lane >> 4) * 4;
#pragma unroll
  for (int mi = 0; mi < 4; ++mi) {
#pragma unroll
    for (int ni = 0; ni < 4; ++ni) {
      int c = bn * BN + wn + ni * 16 + cl;
      int r0 = bm * BM + wm + mi * 16 + rl;
#pragma unroll
      for (int j = 0; j < 4; ++j) {
        int r = r0 + j;
        float v = acc[mi][ni][j];
        if (MODE == 0) {
          ((float*)Cptr)[(size_t)r * N + c] = v;
        } else if (MODE == 1) {
          ((short*)Cptr)[(size_t)r * N + c] = f2bf(tanhf(v));
        } else {
          int b = r & 31, l = r >> 5;
          ((float*)Cptr)[(size_t)(b * L_ + l) * N + c] = v + bias[c];
        }
      }
    }
  }
}

// ---------------- SRU scan: per (b,d) lane, sequential over L ---------------
__global__ void sru_scan_kernel(const float* __restrict__ U, const float* __restrict__ bvec,
                                const float* __restrict__ xin, const float* __restrict__ c0,
                                float* __restrict__ hf, short* __restrict__ hb,
                                float* __restrict__ clast) {
  int idx = blockIdx.x * 64 + threadIdx.x;  // < B*D = 16384
  int b = idx >> 9, d = idx & 511;
  float c = c0[idx];
  float bfb = bvec[d], brb = bvec[512 + d];
#pragma unroll 4
  for (int l = 0; l < L_; ++l) {
    size_t u = ((size_t)l * B_ + b) * 1536;
    float z = U[u + d];
    float fp = U[u + 512 + d];
    float rp = U[u + 1024 + d];
    float f = 1.f / (1.f + expf(-(fp + bfb)));
    float r = 1.f / (1.f + expf(-(rp + brb)));
    c = f * c + (1.f - f) * z;
    float x = xin[((size_t)l * B_ + b) * 512 + d];
    float h = r * tanhf(c) + (1.f - r) * x;
    size_t o = ((size_t)l * B_ + b) * 512 + d;
    hf[o] = h;
    hb[o] = f2bf(h);
  }
  clast[idx] = c;
}

// -------- fused scores + softmax: one 256-thread block per (l,b) row --------
__global__ __launch_bounds__(256) void scores_softmax_kernel(
    const float* __restrict__ x, const float* __restrict__ enc,
    float* __restrict__ align_out) {
  __shared__ float q[512];
  __shared__ float sc[64];
  int r = blockIdx.x;       // l*B + b
  int b = r & (B_ - 1);
  int tid = threadIdx.x;
  int wave = tid >> 6, lane = tid & 63;
  for (int d = tid; d < 512; d += 256) q[d] = x[(size_t)r * 512 + d];
  __syncthreads();
#pragma unroll
  for (int si = 0; si < 16; ++si) {
    int s = wave * 16 + si;
    const float* m = enc + ((size_t)s * B_ + b) * 512;
    float a = 0.f;
#pragma unroll
    for (int k = 0; k < 8; ++k) a += q[lane + k * 64] * m[lane + k * 64];
    for (int o = 32; o > 0; o >>= 1) a += __shfl_xor(a, o);
    if (lane == 0) sc[s] = a;
  }
  __syncthreads();
  if (tid < 64) {
    float v = sc[tid];
    float mx = v;
    for (int o = 32; o > 0; o >>= 1) mx = fmaxf(mx, __shfl_xor(mx, o));
    float e = expf(v - mx);
    float sm = e;
    for (int o = 32; o > 0; o >>= 1) sm += __shfl_xor(sm, o);
    align_out[(size_t)r * S_ + tid] = e / sm;
  }
}

// -------- ctx = align @ mem, then concat [ctx, q] as bf16 -------------------
__global__ void ctx_concat_kernel(const float* __restrict__ align_in, const float* __restrict__ enc,
                                  const short* __restrict__ xb, short* __restrict__ cat) {
  __shared__ float al[64];
  int r = blockIdx.x;       // l*B + b
  int b = r & (B_ - 1);
  int tid = threadIdx.x;    // 256
  if (tid < 64) al[tid] = align_in[(size_t)r * S_ + tid];
  __syncthreads();
  for (int d = tid; d < 512; d += 256) {
    float acc = 0.f;
#pragma unroll 8
    for (int s = 0; s < S_; ++s) acc += al[s] * enc[((size_t)s * B_ + b) * 512 + d];
    cat[(size_t)r * 1024 + d] = f2bf(acc);
    cat[(size_t)r * 1024 + 512 + d] = xb[(size_t)r * 512 + d];
  }
}

extern "C" void kernel_launch(void* const* d_in, const int* in_sizes, int n_in,
                              void* d_out, int out_size, void* d_ws, size_t ws_size,
                              hipStream_t stream) {
  const int* rnn = (const int*)d_in[0];
  const float* h0 = (const float*)d_in[1];
  const float* enc = (const float*)d_in[2];
  const float* tab = (const float*)d_in[3];
  const float* sruW = (const float*)d_in[4];
  const float* srub = (const float*)d_in[5];
  const float* attnW = (const float*)d_in[6];
  const float* outW = (const float*)d_in[7];
  const float* outb = (const float*)d_in[8];
  float* out = (float*)d_out;

  char* ws = (char*)d_ws;
  size_t off = 0;
  auto alloc = [&](size_t bytes) {
    char* p = ws + off;
    off += (bytes + 255) & ~(size_t)255;
    return p;
  };
  float* xf = (float*)alloc(4ull * 2048 * 512);
  float* xf2 = (float*)alloc(4ull * 2048 * 512);
  short* xb = (short*)alloc(2ull * 2048 * 512);
  float* U = (float*)alloc(4ull * 2048 * 1536);
  short* WTs = (short*)alloc(2ull * 2 * 1536 * 512);
  short* WTa = (short*)alloc(2ull * 512 * 1024);
  short* WTo = (short*)alloc(2ull * 32000 * 512);
  float* algn = (float*)alloc(4ull * 2048 * 64);
  short* cat = (short*)alloc(2ull * 2048 * 1024);
  short* ah = (short*)alloc(2ull * 2048 * 512);

  dim3 tb(32, 8);
  for (int l = 0; l < NL_; ++l)
    transpose_f32_bf16<<<dim3(48, 16), tb, 0, stream>>>(
        sruW + (size_t)l * 512 * 1536, WTs + (size_t)l * 1536 * 512, 512, 1536);
  transpose_f32_bf16<<<dim3(16, 32), tb, 0, stream>>>(attnW, WTa, 1024, 512);
  transpose_f32_bf16<<<dim3(1000, 16), tb, 0, stream>>>(outW, WTo, 512, 32000);

  embed_kernel<<<4096, 256, 0, stream>>>(rnn, tab, xf, xb);

  float* hidden_out = out + (size_t)B_ * L_ * V_;

  // layer 0: x(=embed) -> h in xf2/xb
  gemm_kernel<0><<<192, 256, 0, stream>>>(xb, WTs, U, nullptr, 2048, 1536, 512, 16);
  sru_scan_kernel<<<256, 64, 0, stream>>>(U, srub, xf, h0, xf2, xb, hidden_out);
  // layer 1: h1 -> final h in xf/xb
  gemm_kernel<0><<<192, 256, 0, stream>>>(xb, WTs + 1536 * 512, U, nullptr, 2048, 1536, 512, 16);
  sru_scan_kernel<<<256, 64, 0, stream>>>(U, srub + 1024, xf2, h0 + B_ * D_, xf, xb,
                                          hidden_out + B_ * D_);

  scores_softmax_kernel<<<2048, 256, 0, stream>>>(xf, enc, algn);
  ctx_concat_kernel<<<2048, 256, 0, stream>>>(algn, enc, xb, cat);

  // attn_h = tanh(concat @ attn_W) as bf16
  gemm_kernel<1><<<64, 256, 0, stream>>>(cat, WTa, ah, nullptr, 2048, 512, 1024, 16);
  // output = attn_h @ out_W + out_b, remapped to [B,L,V]
  gemm_kernel<2><<<4000, 256, 0, stream>>>(ah, WTo, out, outb, 2048, 32000, 512, 16);
}

// Round 3
// 274.613 us; speedup vs baseline: 1.3189x; 1.2036x over previous
//
#include <hip/hip_runtime.h>
#include <hip/hip_bf16.h>

#define L_ 64
#define B_ 32
#define S_ 64
#define D_ 512
#define V_ 32000
#define NL_ 2

typedef __attribute__((ext_vector_type(8))) short bf16x8;
typedef __attribute__((ext_vector_type(4))) float f32x4;

static __device__ __forceinline__ short f2bf(float f) {
  union { float f; unsigned u; } x; x.f = f;
  unsigned r = (x.u + 0x7FFFu + ((x.u >> 16) & 1u)) >> 16;
  return (short)r;
}

#define GLOAD_LDS16(g, l)                                                     \
  __builtin_amdgcn_global_load_lds(                                           \
      (const __attribute__((address_space(1))) void*)(g),                     \
      (__attribute__((address_space(3))) void*)(l), 16, 0, 0)

// ---------------- embedding gather: x[l,b,d] = tab[tok[l,b], d] -------------
__global__ void embed_kernel(const int* __restrict__ tok, const float* __restrict__ tab,
                             float* __restrict__ xf, short* __restrict__ xb) {
  int i = blockIdx.x * 256 + threadIdx.x;  // < L*B*D = 1048576
  int d = i & (D_ - 1);
  int lb = i >> 9;
  float v = tab[(size_t)tok[lb] * D_ + d];
  xf[i] = v;
  xb[i] = f2bf(v);
}

// ------------- f32 [K,N] -> bf16 [N,K] transpose (LDS-tiled) ----------------
__global__ void transpose_f32_bf16(const float* __restrict__ in, short* __restrict__ out,
                                   int K, int N) {
  __shared__ float tile[32][33];
  int x = blockIdx.x * 32 + threadIdx.x;  // N index
  int y0 = blockIdx.y * 32;               // K base
  for (int j = threadIdx.y; j < 32; j += 8) {
    int y = y0 + j;
    tile[j][threadIdx.x] = (x < N && y < K) ? in[(size_t)y * N + x] : 0.f;
  }
  __syncthreads();
  int xo = y0 + threadIdx.x;              // K index
  int yo0 = blockIdx.x * 32;              // N base
  for (int j = threadIdx.y; j < 32; j += 8) {
    int yo = yo0 + j;
    if (yo < N && xo < K) out[(size_t)yo * K + xo] = f2bf(tile[threadIdx.x][j]);
  }
}

// ---------------- generic bf16 MFMA GEMM: C = A[M,K] * BT[N,K]^T ------------
// 2-phase double-buffered pipeline (T3 minimum): STAGE(t+1) issued before
// ds_read+MFMA(t); one barrier per K-tile. XCD-chunked bijective swizzle,
// bm-fastest so consecutive blocks share a B-tile.
// MODE 0: write f32 C[M,N]
// MODE 1: write bf16 tanh(C)[M,N]
// MODE 2: write f32 C[row-remap (l*B+b)->(b*L+l)][N] + bias[n]
#define BM 128
#define BN 128
#define BK 64

template <int MODE>
__global__ __launch_bounds__(256) void gemm_kernel(
    const short* __restrict__ A, const short* __restrict__ BT,
    void* __restrict__ Cptr, const float* __restrict__ bias,
    int M, int N, int K, int nbm) {
  // ---- XCD-chunked swizzle (requires gridDim.x % 8 == 0) ----
  const int nwg = gridDim.x;
  const int qc = nwg >> 3;
  const int bid = blockIdx.x;
  const int wg = (bid & 7) * qc + (bid >> 3);
  const int bm = wg % nbm;
  const int bn = wg / nbm;

  __shared__ __align__(16) short la[2][BM * BK];
  __shared__ __align__(16) short lb[2][BN * BK];
  const int tid = threadIdx.x;
  const int wave = tid >> 6, lane = tid & 63;
  const int wm = (wave >> 1) * 64, wn = (wave & 1) * 64;

  f32x4 acc[4][4] = {};

  const int lrow = lane >> 3;   // row within 8-row chunk
  const int lslot = lane & 7;   // 16B slot within 128B row
  const short* Abase = A + (size_t)(bm * BM) * K;
  const short* Bbase = BT + (size_t)(bn * BN) * K;

  auto stage = [&](int buf, int k0) {
#pragma unroll
    for (int c = 0; c < 4; ++c) {
      int chunk = wave * 4 + c;
      int row = chunk * 8 + lrow;
      int slot = lslot ^ (row & 7);
      GLOAD_LDS16(Abase + (size_t)row * K + k0 + slot * 8, &la[buf][chunk * 512]);
      GLOAD_LDS16(Bbase + (size_t)row * K + k0 + slot * 8, &lb[buf][chunk * 512]);
    }
  };

  stage(0, 0);
  __syncthreads();  // compiler drains vmcnt(0) before s_barrier

  const int nt = K / BK;
  int cur = 0;
  for (int t = 0; t < nt; ++t) {
    if (t + 1 < nt) stage(cur ^ 1, (t + 1) * BK);  // prefetch overlaps compute
#pragma unroll
    for (int kk = 0; kk < 2; ++kk) {
      bf16x8 af[4], bfr[4];
#pragma unroll
      for (int mi = 0; mi < 4; ++mi) {
        int row = wm + mi * 16 + (lane & 15);
        int slot = (kk * 4 + (lane >> 4)) ^ (row & 7);
        af[mi] = *(const bf16x8*)&la[cur][row * 64 + slot * 8];
      }
#pragma unroll
      for (int ni = 0; ni < 4; ++ni) {
        int row = wn + ni * 16 + (lane & 15);
        int slot = (kk * 4 + (lane >> 4)) ^ (row & 7);
        bfr[ni] = *(const bf16x8*)&lb[cur][row * 64 + slot * 8];
      }
#pragma unroll
      for (int mi = 0; mi < 4; ++mi)
#pragma unroll
        for (int ni = 0; ni < 4; ++ni)
          acc[mi][ni] = __builtin_amdgcn_mfma_f32_16x16x32_bf16(
              af[mi], bfr[ni], acc[mi][ni], 0, 0, 0);
    }
    __syncthreads();  // drains prefetch vmcnt; protects buf reuse
    cur ^= 1;
  }

  const int cl = lane & 15;
  const int rl = (lane >> 4) * 4;
#pragma unroll
  for (int mi = 0; mi < 4; ++mi) {
#pragma unroll
    for (int ni = 0; ni < 4; ++ni) {
      int c = bn * BN + wn + ni * 16 + cl;
      int r0 = bm * BM + wm + mi * 16 + rl;
#pragma unroll
      for (int j = 0; j < 4; ++j) {
        int r = r0 + j;
        float v = acc[mi][ni][j];
        if (MODE == 0) {
          ((float*)Cptr)[(size_t)r * N + c] = v;
        } else if (MODE == 1) {
          ((short*)Cptr)[(size_t)r * N + c] = f2bf(tanhf(v));
        } else {
          int b = r & 31, l = r >> 5;
          ((float*)Cptr)[(size_t)(b * L_ + l) * N + c] = v + bias[c];
        }
      }
    }
  }
}

// ---------------- SRU scan: per (b,d) lane, 8-step chunked prefetch ---------
__global__ void sru_scan_kernel(const float* __restrict__ U, const float* __restrict__ bvec,
                                const float* __restrict__ xin, const float* __restrict__ c0,
                                float* __restrict__ hf, short* __restrict__ hb,
                                float* __restrict__ clast) {
  int idx = blockIdx.x * 64 + threadIdx.x;  // < B*D = 16384
  int b = idx >> 9, d = idx & 511;
  float c = c0[idx];
  const float bfb = bvec[d], brb = bvec[512 + d];
  const float* Ub = U + (size_t)b * 1536 + d;
  const float* Xb = xin + (size_t)b * 512 + d;

  for (int l0 = 0; l0 < L_; l0 += 8) {
    float z[8], fp[8], rp[8], xv[8];
#pragma unroll
    for (int j = 0; j < 8; ++j) {
      size_t u = (size_t)(l0 + j) * B_ * 1536;
      z[j] = Ub[u];
      fp[j] = Ub[u + 512];
      rp[j] = Ub[u + 1024];
      xv[j] = Xb[(size_t)(l0 + j) * B_ * 512];
    }
#pragma unroll
    for (int j = 0; j < 8; ++j) {
      float f = 1.f / (1.f + expf(-(fp[j] + bfb)));
      float r = 1.f / (1.f + expf(-(rp[j] + brb)));
      c = f * c + (1.f - f) * z[j];
      float h = r * tanhf(c) + (1.f - r) * xv[j];
      size_t o = ((size_t)(l0 + j) * B_ + b) * 512 + d;
      hf[o] = h;
      hb[o] = f2bf(h);
    }
  }
  clast[idx] = c;
}

// ------ fused attention: scores + softmax + ctx + concat, per (l,b) row -----
__global__ __launch_bounds__(256) void attn_fused_kernel(
    const float* __restrict__ x, const float* __restrict__ enc,
    const short* __restrict__ xq, short* __restrict__ cat) {
  __shared__ float q[512];
  __shared__ float al[64];
  int r = blockIdx.x;       // l*B + b
  int b = r & (B_ - 1);
  int tid = threadIdx.x;
  int wave = tid >> 6, lane = tid & 63;
  for (int d = tid; d < 512; d += 256) {
    q[d] = x[(size_t)r * 512 + d];
    cat[(size_t)r * 1024 + 512 + d] = xq[(size_t)r * 512 + d];
  }
  __syncthreads();
  // scores: wave w computes s = w*16 .. w*16+15
#pragma unroll
  for (int si = 0; si < 16; ++si) {
    int s = wave * 16 + si;
    const float* m = enc + ((size_t)s * B_ + b) * 512;
    float a = 0.f;
#pragma unroll
    for (int k = 0; k < 8; ++k) a += q[lane + k * 64] * m[lane + k * 64];
    for (int o = 32; o > 0; o >>= 1) a += __shfl_xor(a, o);
    if (lane == 0) al[s] = a;
  }
  __syncthreads();
  if (tid < 64) {
    float v = al[tid];
    float mx = v;
    for (int o = 32; o > 0; o >>= 1) mx = fmaxf(mx, __shfl_xor(mx, o));
    float e = expf(v - mx);
    float sm = e;
    for (int o = 32; o > 0; o >>= 1) sm += __shfl_xor(sm, o);
    al[tid] = e / sm;
  }
  __syncthreads();
  // ctx = align @ mem (enc rows are L2-hot from the scores pass)
  for (int d = tid; d < 512; d += 256) {
    float acc = 0.f;
#pragma unroll 16
    for (int s = 0; s < S_; ++s) acc += al[s] * enc[((size_t)s * B_ + b) * 512 + d];
    cat[(size_t)r * 1024 + d] = f2bf(acc);
  }
}

extern "C" void kernel_launch(void* const* d_in, const int* in_sizes, int n_in,
                              void* d_out, int out_size, void* d_ws, size_t ws_size,
                              hipStream_t stream) {
  const int* rnn = (const int*)d_in[0];
  const float* h0 = (const float*)d_in[1];
  const float* enc = (const float*)d_in[2];
  const float* tab = (const float*)d_in[3];
  const float* sruW = (const float*)d_in[4];
  const float* srub = (const float*)d_in[5];
  const float* attnW = (const float*)d_in[6];
  const float* outW = (const float*)d_in[7];
  const float* outb = (const float*)d_in[8];
  float* out = (float*)d_out;

  char* ws = (char*)d_ws;
  size_t off = 0;
  auto alloc = [&](size_t bytes) {
    char* p = ws + off;
    off += (bytes + 255) & ~(size_t)255;
    return p;
  };
  float* xf = (float*)alloc(4ull * 2048 * 512);
  float* xf2 = (float*)alloc(4ull * 2048 * 512);
  short* xb = (short*)alloc(2ull * 2048 * 512);
  float* U = (float*)alloc(4ull * 2048 * 1536);
  short* WTs = (short*)alloc(2ull * 2 * 1536 * 512);
  short* WTa = (short*)alloc(2ull * 512 * 1024);
  short* WTo = (short*)alloc(2ull * 32000 * 512);
  short* cat = (short*)alloc(2ull * 2048 * 1024);
  short* ah = (short*)alloc(2ull * 2048 * 512);

  dim3 tb(32, 8);
  for (int l = 0; l < NL_; ++l)
    transpose_f32_bf16<<<dim3(48, 16), tb, 0, stream>>>(
        sruW + (size_t)l * 512 * 1536, WTs + (size_t)l * 1536 * 512, 512, 1536);
  transpose_f32_bf16<<<dim3(16, 32), tb, 0, stream>>>(attnW, WTa, 1024, 512);
  transpose_f32_bf16<<<dim3(1000, 16), tb, 0, stream>>>(outW, WTo, 512, 32000);

  embed_kernel<<<4096, 256, 0, stream>>>(rnn, tab, xf, xb);

  float* hidden_out = out + (size_t)B_ * L_ * V_;

  // layer 0: x(=embed) -> h in xf2/xb
  gemm_kernel<0><<<192, 256, 0, stream>>>(xb, WTs, U, nullptr, 2048, 1536, 512, 16);
  sru_scan_kernel<<<256, 64, 0, stream>>>(U, srub, xf, h0, xf2, xb, hidden_out);
  // layer 1: h1 -> final h in xf/xb
  gemm_kernel<0><<<192, 256, 0, stream>>>(xb, WTs + 1536 * 512, U, nullptr, 2048, 1536, 512, 16);
  sru_scan_kernel<<<256, 64, 0, stream>>>(U, srub + 1024, xf2, h0 + B_ * D_, xf, xb,
                                          hidden_out + B_ * D_);

  // fused attention: scores+softmax+ctx+concat
  attn_fused_kernel<<<2048, 256, 0, stream>>>(xf, enc, xb, cat);

  // attn_h = tanh(concat @ attn_W) as bf16
  gemm_kernel<1><<<64, 256, 0, stream>>>(cat, WTa, ah, nullptr, 2048, 512, 1024, 16);
  // output = attn_h @ out_W + out_b, remapped to [B,L,V]
  gemm_kernel<2><<<4000, 256, 0, stream>>>(ah, WTo, out, outb, 2048, 32000, 512, 16);
}